// Round 11
// baseline (169.923 us; speedup 1.0000x reference)
//
#include <hip/hip_runtime.h>
#include <stdint.h>

#define NN   4096
#define NE   131072
#define KIN  512
#define NH   8
#define HF   256
#define SLOPE 0.2f
#define MAXJ 256
#define REP  10   // DIAGNOSTIC: x10 internal replication to surface kernels in rocprof top-5

typedef __attribute__((ext_vector_type(8))) short bf16x8;
typedef __attribute__((ext_vector_type(4))) float f32x4;

// ws layout: [0,2MB) bitmap | [2,4MB) gbf bf16 | [4MB,+128K) el | +128K er |
//            [4.25MB,+256K) Btbf (W_fc^T bf16)

__device__ __forceinline__ unsigned short f2bf(float x) {  // RTN-even f32->bf16
  unsigned u = __builtin_bit_cast(unsigned, x);
  u += 0x7FFFu + ((u >> 16) & 1u);
  return (unsigned short)(u >> 16);
}
__device__ __forceinline__ float bf2f(unsigned short x) {
  unsigned u = ((unsigned)x) << 16;
  return __builtin_bit_cast(float, u);
}
__device__ __forceinline__ unsigned pack2(float lo, float hi) {
  return (unsigned)f2bf(lo) | ((unsigned)f2bf(hi) << 16);
}

// K1: blocks 0..511 clear bitmap; 512..639 W_fc -> B^T bf16 (32x32 tile transpose)
__global__ __launch_bounds__(256) void prep_k(const float* __restrict__ B,
                                              unsigned* __restrict__ bitmap,
                                              unsigned short* __restrict__ Btbf) {
  __shared__ float tile[32][33];
  const int b = blockIdx.x, t = threadIdx.x;
  for (int rep = 0; rep < REP; ++rep) {
    if (b < 512) {
      ((float4*)bitmap)[b * 256 + t] = make_float4(0.f, 0.f, 0.f, 0.f);
    } else {
      int bb = b - 512;
      int k0 = (bb >> 3) * 32, n0 = (bb & 7) * 32;
      int lr = t >> 3, lc = (t & 7) * 4;
      float4 v = *(const float4*)&B[(size_t)(k0 + lr) * HF + n0 + lc];
      tile[lr][lc] = v.x; tile[lr][lc + 1] = v.y; tile[lr][lc + 2] = v.z; tile[lr][lc + 3] = v.w;
      __syncthreads();
      ushort4 o;
      o.x = f2bf(tile[lc + 0][lr]); o.y = f2bf(tile[lc + 1][lr]);
      o.z = f2bf(tile[lc + 2][lr]); o.w = f2bf(tile[lc + 3][lr]);
      *(ushort4*)&Btbf[(size_t)(n0 + lr) * KIN + k0 + lc] = o;
      __syncthreads();   // rep boundary: tile reuse
    }
  }
}

// K2: blocks 0..1023 = 32x32 MFMA GEMM tiles (128 M x 8 heads), BK=64, dbuf,
//     A reg-staged from h, B via global_load_lds; fused el/er epilogue.
//     Blocks 1024..1551 = build_adj (bitmap atomicOr, idempotent under REP).
__global__ __launch_bounds__(256) void gemm_adj_k(const float* __restrict__ h,
                                                  const unsigned short* __restrict__ Bt,
                                                  const float* __restrict__ Wa,
                                                  unsigned short* __restrict__ gbf,
                                                  float* __restrict__ el,
                                                  float* __restrict__ er,
                                                  const int* __restrict__ ei,
                                                  const float* __restrict__ mask,
                                                  unsigned* __restrict__ bitmap) {
  __shared__ unsigned short smem[2][4096];  // per buf: A[32][64]@0, B[32][64]@2048
  const int bx = blockIdx.x, t = threadIdx.x;
  if (bx >= 1024) {
    for (int rep = 0; rep < REP; ++rep) {
      int k = (bx - 1024) * 256 + t;
      int s, d; float m;
      if (k < NE) { s = ei[k]; d = ei[NE + k]; m = mask[k]; }
      else        { s = k - NE; d = s; m = 1.0f; }
      if (m != 0.0f) atomicOr(&bitmap[s * 128 + (d >> 5)], 1u << (d & 31));
    }
    return;
  }
  const int gx = bx & 127, gy = bx >> 7;
  const int row0 = gx * 32, col0 = gy * 32;
  const int w = t >> 6, l = t & 63;
  const int wr = w >> 1, wc = w & 1;

  const int srow = (w << 3) + (l >> 3);
  const int sc   = l & 7;
  const int aoff = srow * 64 + ((sc ^ (srow & 7)) << 3);
  const float* gA = &h[(size_t)(row0 + srow) * KIN + sc * 8];
  const int schB = sc ^ (srow & 7);
  const unsigned short* gB = &Bt[(size_t)(col0 + srow) * KIN + schB * 8];

#define BSTAGE(bf, ks)                                                                            \
  __builtin_amdgcn_global_load_lds(                                                               \
      (const __attribute__((address_space(1))) unsigned int*)(gB + (size_t)(ks) * 64),            \
      (__attribute__((address_space(3))) unsigned int*)(&smem[bf][2048 + w * 512]), 16, 0, 0)

  for (int rep = 0; rep < REP; ++rep) {
    f32x4 acc = {};
    {
      float4 va0 = *(const float4*)(gA);
      float4 va1 = *(const float4*)(gA + 4);
      BSTAGE(0, 0);
      uint4 w4 = {pack2(va0.x, va0.y), pack2(va0.z, va0.w),
                  pack2(va1.x, va1.y), pack2(va1.z, va1.w)};
      *(uint4*)&smem[0][aoff] = w4;
    }
    __syncthreads();

    const int lrow = l & 15, kg = l >> 4;
    const int ar = wr * 16 + lrow, br = wc * 16 + lrow;
    for (int ks = 0; ks < 8; ++ks) {
      const int bf = ks & 1;
      float4 na0, na1;
      if (ks < 7) {
        na0 = *(const float4*)(gA + (ks + 1) * 64);
        na1 = *(const float4*)(gA + (ks + 1) * 64 + 4);
        BSTAGE(bf ^ 1, ks + 1);
      }
      bf16x8 a0 = *(const bf16x8*)&smem[bf][ar * 64 + ((kg ^ (ar & 7)) << 3)];
      bf16x8 a1 = *(const bf16x8*)&smem[bf][ar * 64 + (((4 + kg) ^ (ar & 7)) << 3)];
      bf16x8 b0 = *(const bf16x8*)&smem[bf][2048 + br * 64 + ((kg ^ (br & 7)) << 3)];
      bf16x8 b1 = *(const bf16x8*)&smem[bf][2048 + br * 64 + (((4 + kg) ^ (br & 7)) << 3)];
      acc = __builtin_amdgcn_mfma_f32_16x16x32_bf16(a0, b0, acc, 0, 0, 0);
      acc = __builtin_amdgcn_mfma_f32_16x16x32_bf16(a1, b1, acc, 0, 0, 0);
      if (ks < 7) {
        uint4 w4 = {pack2(na0.x, na0.y), pack2(na0.z, na0.w),
                    pack2(na1.x, na1.y), pack2(na1.z, na1.w)};
        *(uint4*)&smem[bf ^ 1][aoff] = w4;
      }
      __syncthreads();
    }

    // C/D: col=lane&15, row=(lane>>4)*4+q
    const int crow = (l >> 4) * 4, ccol = l & 15;
    const int gr0 = row0 + wr * 16 + crow, gc = col0 + wc * 16 + ccol;
#pragma unroll
    for (int q = 0; q < 4; ++q) gbf[(size_t)(gr0 + q) * HF + gc] = f2bf(acc[q]);

    float* red = (float*)smem;
    const int f = wc * 16 + ccol;
    const float wal = Wa[f], war = Wa[32 + f];
#pragma unroll
    for (int q = 0; q < 4; ++q) {
      float pel = acc[q] * wal, per = acc[q] * war;
#pragma unroll
      for (int m = 8; m >= 1; m >>= 1) { pel += __shfl_xor(pel, m); per += __shfl_xor(per, m); }
      if (ccol == 0) {
        int rl = wr * 16 + crow + q;
        red[wc * 32 + rl] = pel;
        red[64 + wc * 32 + rl] = per;
      }
    }
    __syncthreads();
    if (t < 32) {
      el[(row0 + t) * NH + gy] = red[t] + red[32 + t];
      er[(row0 + t) * NH + gy] = red[64 + t] + red[96 + t];
    }
    __syncthreads();   // rep boundary: smem reuse
  }
#undef BSTAGE
}

// K3: one WAVE per row (4 rows/block), 4-way MLP gather.
__global__ __launch_bounds__(256) void attn_k(const unsigned* __restrict__ bitmap,
                                              const unsigned short* __restrict__ gbf,
                                              const float* __restrict__ el_,
                                              const float* __restrict__ er_,
                                              float* __restrict__ out) {
  __shared__ unsigned short jl[4][MAXJ];
  const int t = threadIdx.x, wv = t >> 6, l = t & 63;
  const int i = blockIdx.x * 4 + wv;

  for (int rep = 0; rep < REP; ++rep) {
    unsigned w0 = bitmap[i * 128 + l];
    unsigned w1 = bitmap[i * 128 + 64 + l];
    int cnt = __popc(w0) + __popc(w1);
    int incl = cnt;
#pragma unroll
    for (int d = 1; d < 64; d <<= 1) {
      int u = __shfl_up(incl, d);
      if (l >= d) incl += u;
    }
    int total = __shfl(incl, 63);
    if (total > MAXJ) total = MAXJ;
    int off = incl - cnt;
    unsigned short* J = jl[wv];             // wave-private: same-wave lgkmcnt ordering suffices
    while (w0) {
      int b = __ffs(w0) - 1;
      if (off < MAXJ) J[off] = (unsigned short)(l * 32 + b);
      ++off; w0 &= w0 - 1;
    }
    while (w1) {
      int b = __ffs(w1) - 1;
      if (off < MAXJ) J[off] = (unsigned short)((64 + l) * 32 + b);
      ++off; w1 &= w1 - 1;
    }
    __syncthreads();

    const int hh = l >> 3;
    const float elh = el_[i * NH + hh];
    const unsigned short* gp = gbf + (size_t)l * 4;
    f32x4 accA = {}, accB = {};
    float den0 = 0.f, den1 = 0.f;
    int k = 0;
    for (; k + 4 <= total; k += 4) {
      int j0 = J[k], j1 = J[k + 1], j2 = J[k + 2], j3 = J[k + 3];
      float e0 = elh + er_[j0 * NH + hh];
      float e1 = elh + er_[j1 * NH + hh];
      float e2 = elh + er_[j2 * NH + hh];
      float e3 = elh + er_[j3 * NH + hh];
      ushort4 g0 = *(const ushort4*)(gp + (size_t)j0 * HF);
      ushort4 g1 = *(const ushort4*)(gp + (size_t)j1 * HF);
      ushort4 g2 = *(const ushort4*)(gp + (size_t)j2 * HF);
      ushort4 g3 = *(const ushort4*)(gp + (size_t)j3 * HF);
      float l0 = e0 > 0.f ? e0 : SLOPE * e0;
      float l1 = e1 > 0.f ? e1 : SLOPE * e1;
      float l2 = e2 > 0.f ? e2 : SLOPE * e2;
      float l3 = e3 > 0.f ? e3 : SLOPE * e3;
      float wg0 = __expf(l0), wg1 = __expf(l1), wg2 = __expf(l2), wg3 = __expf(l3);
      den0 += wg0 + wg2; den1 += wg1 + wg3;
      accA[0] += wg0 * bf2f(g0.x); accB[0] += wg1 * bf2f(g1.x);
      accA[1] += wg0 * bf2f(g0.y); accB[1] += wg1 * bf2f(g1.y);
      accA[2] += wg0 * bf2f(g0.z); accB[2] += wg1 * bf2f(g1.z);
      accA[3] += wg0 * bf2f(g0.w); accB[3] += wg1 * bf2f(g1.w);
      accA[0] += wg2 * bf2f(g2.x); accB[0] += wg3 * bf2f(g3.x);
      accA[1] += wg2 * bf2f(g2.y); accB[1] += wg3 * bf2f(g3.y);
      accA[2] += wg2 * bf2f(g2.z); accB[2] += wg3 * bf2f(g3.z);
      accA[3] += wg2 * bf2f(g2.w); accB[3] += wg3 * bf2f(g3.w);
    }
    for (; k < total; ++k) {
      int j0 = J[k];
      float e0 = elh + er_[j0 * NH + hh];
      float l0 = e0 > 0.f ? e0 : SLOPE * e0;
      float wg0 = __expf(l0);
      ushort4 g0 = *(const ushort4*)(gp + (size_t)j0 * HF);
      den0 += wg0;
      accA[0] += wg0 * bf2f(g0.x); accA[1] += wg0 * bf2f(g0.y);
      accA[2] += wg0 * bf2f(g0.z); accA[3] += wg0 * bf2f(g0.w);
    }
    float inv = 1.f / (den0 + den1);
    float4 o = make_float4((accA[0] + accB[0]) * inv, (accA[1] + accB[1]) * inv,
                           (accA[2] + accB[2]) * inv, (accA[3] + accB[3]) * inv);
    *(float4*)&out[(size_t)i * HF + l * 4] = o;
    __syncthreads();   // rep boundary
  }
}

extern "C" void kernel_launch(void* const* d_in, const int* in_sizes, int n_in,
                              void* d_out, int out_size, void* d_ws, size_t ws_size,
                              hipStream_t stream) {
  const float* h      = (const float*)d_in[0];
  const int*   ei     = (const int*)d_in[1];
  const float* mask   = (const float*)d_in[2];
  const float* W_fc   = (const float*)d_in[3];
  const float* W_attn = (const float*)d_in[4];
  float* out = (float*)d_out;

  char* ws = (char*)d_ws;
  unsigned* bitmap      = (unsigned*)ws;                                          // 2 MB
  unsigned short* gbf   = (unsigned short*)(ws + (size_t)2 * 1024 * 1024);        // 2 MB
  float* el             = (float*)(ws + (size_t)4 * 1024 * 1024);                 // 128 KB
  float* er             = (float*)(ws + (size_t)4 * 1024 * 1024 + 128 * 1024);    // 128 KB
  unsigned short* Btbf  = (unsigned short*)(ws + (size_t)4 * 1024 * 1024 + 256 * 1024);  // 256 KB

  prep_k<<<640, 256, 0, stream>>>(W_fc, bitmap, Btbf);
  gemm_adj_k<<<1024 + 528, 256, 0, stream>>>(h, Btbf, W_attn, gbf, el, er, ei, mask, bitmap);
  attn_k<<<NN / 4, 256, 0, stream>>>(bitmap, gbf, el, er, out);
}

// Round 12
// 48.513 us; speedup vs baseline: 3.5026x; 3.5026x over previous
//
#include <hip/hip_runtime.h>
#include <stdint.h>

#define NN   4096
#define NE   131072
#define KIN  512
#define NH   8
#define HF   256
#define SLOPE 0.2f
#define MAXJ 256

typedef __attribute__((ext_vector_type(8))) short bf16x8;
typedef __attribute__((ext_vector_type(4))) float f32x4;
typedef __attribute__((ext_vector_type(4))) unsigned int u32x4;

// ws layout: [0,2MB) bitmap | [2,4MB) gbf bf16 | [4MB,+128K) el | +128K er |
//            [4.25MB,+256K) Btbf (W_fc^T bf16)

__device__ __forceinline__ unsigned short f2bf(float x) {  // RTN-even f32->bf16
  unsigned u = __builtin_bit_cast(unsigned, x);
  u += 0x7FFFu + ((u >> 16) & 1u);
  return (unsigned short)(u >> 16);
}
__device__ __forceinline__ float bf2f(unsigned short x) {
  unsigned u = ((unsigned)x) << 16;
  return __builtin_bit_cast(float, u);
}
__device__ __forceinline__ unsigned pack2(float lo, float hi) {
  return (unsigned)f2bf(lo) | ((unsigned)f2bf(hi) << 16);
}

// K1: blocks 0..511 clear bitmap; 512..639 W_fc -> B^T bf16 (32x32 tile transpose)
__global__ __launch_bounds__(256) void prep_k(const float* __restrict__ B,
                                              unsigned* __restrict__ bitmap,
                                              unsigned short* __restrict__ Btbf) {
  __shared__ float tile[32][33];
  const int b = blockIdx.x, t = threadIdx.x;
  if (b < 512) {
    ((float4*)bitmap)[b * 256 + t] = make_float4(0.f, 0.f, 0.f, 0.f);
  } else {
    int bb = b - 512;
    int k0 = (bb >> 3) * 32, n0 = (bb & 7) * 32;
    int lr = t >> 3, lc = (t & 7) * 4;
    float4 v = *(const float4*)&B[(size_t)(k0 + lr) * HF + n0 + lc];
    tile[lr][lc] = v.x; tile[lr][lc + 1] = v.y; tile[lr][lc + 2] = v.z; tile[lr][lc + 3] = v.w;
    __syncthreads();
    ushort4 o;
    o.x = f2bf(tile[lc + 0][lr]); o.y = f2bf(tile[lc + 1][lr]);
    o.z = f2bf(tile[lc + 2][lr]); o.w = f2bf(tile[lc + 3][lr]);
    *(ushort4*)&Btbf[(size_t)(n0 + lr) * KIN + k0 + lc] = o;
  }
}

// K2: blocks 0..1023 = 32x32 MFMA GEMM tiles (128 M x 8 heads), BARRIER-FREE:
//     A and B fragments loaded straight global->regs per K=32 step (A from h f32
//     + in-reg bf16 pack; B from Btbf). No LDS tile, no K-loop __syncthreads —
//     R11 PMC showed the staged version was latency/barrier-bound (all utils <8%).
//     Fused el/er epilogue. Blocks 1024..1551 = build_adj (bitmap atomicOr).
__global__ __launch_bounds__(256) void gemm_adj_k(const float* __restrict__ h,
                                                  const unsigned short* __restrict__ Bt,
                                                  const float* __restrict__ Wa,
                                                  unsigned short* __restrict__ gbf,
                                                  float* __restrict__ el,
                                                  float* __restrict__ er,
                                                  const int* __restrict__ ei,
                                                  const float* __restrict__ mask,
                                                  unsigned* __restrict__ bitmap) {
  __shared__ float red[128];
  const int bx = blockIdx.x, t = threadIdx.x;
  if (bx >= 1024) {  // ---- build_adj: NE+NN = 135168 = 528*256 exactly ----
    int k = (bx - 1024) * 256 + t;
    int s, d; float m;
    if (k < NE) { s = ei[k]; d = ei[NE + k]; m = mask[k]; }
    else        { s = k - NE; d = s; m = 1.0f; }   // diagonal forced to 1
    if (m != 0.0f) atomicOr(&bitmap[s * 128 + (d >> 5)], 1u << (d & 31));
    return;
  }
  // ---- gemm: 32x32 tile, gy selects the head ----
  const int gx = bx & 127, gy = bx >> 7;
  const int row0 = gx * 32, col0 = gy * 32;
  const int w = t >> 6, l = t & 63;
  const int wr = w >> 1, wc = w & 1;
  const int lrow = l & 15, kg = l >> 4;
  const int ar = wr * 16 + lrow, br = wc * 16 + lrow;

  // lane (lrow,kg) holds k = ks*32 + kg*8 .. +8 of its row (proven mapping)
  const float* pa = &h[(size_t)(row0 + ar) * KIN + kg * 8];
  const unsigned short* pb = &Bt[(size_t)(col0 + br) * KIN + kg * 8];

  f32x4 acc = {};
#pragma unroll 4
  for (int ks = 0; ks < 16; ++ks) {
    float4 a0 = *(const float4*)(pa + ks * 32);
    float4 a1 = *(const float4*)(pa + ks * 32 + 4);
    bf16x8 bfr = *(const bf16x8*)(pb + ks * 32);
    u32x4 up = {pack2(a0.x, a0.y), pack2(a0.z, a0.w),
                pack2(a1.x, a1.y), pack2(a1.z, a1.w)};
    bf16x8 afr = __builtin_bit_cast(bf16x8, up);
    acc = __builtin_amdgcn_mfma_f32_16x16x32_bf16(afr, bfr, acc, 0, 0, 0);
  }

  // C/D: col=lane&15, row=(lane>>4)*4+q  [m89-verified]
  const int crow = (l >> 4) * 4, ccol = l & 15;
  const int gr0 = row0 + wr * 16 + crow, gc = col0 + wc * 16 + ccol;
#pragma unroll
  for (int q = 0; q < 4; ++q) gbf[(size_t)(gr0 + q) * HF + gc] = f2bf(acc[q]);

  // fused el/er: this block's 32 cols == head gy's full f range
  const int f = wc * 16 + ccol;
  const float wal = Wa[f], war = Wa[32 + f];
#pragma unroll
  for (int q = 0; q < 4; ++q) {
    float pel = acc[q] * wal, per = acc[q] * war;
#pragma unroll
    for (int m = 8; m >= 1; m >>= 1) { pel += __shfl_xor(pel, m); per += __shfl_xor(per, m); }
    if (ccol == 0) {
      int rl = wr * 16 + crow + q;
      red[wc * 32 + rl] = pel;
      red[64 + wc * 32 + rl] = per;
    }
  }
  __syncthreads();
  if (t < 32) {
    el[(row0 + t) * NH + gy] = red[t] + red[32 + t];
    er[(row0 + t) * NH + gy] = red[64 + t] + red[96 + t];
  }
}

// K3: one WAVE per row (4 rows/block). Lane l owns output elems [l*4, l*4+4)
// (head l>>3). Wave-local bitmap expand; 4-way MLP gather loop with two
// independent accumulator pairs. No max-subtraction: |e| small -> exp f32-safe.
__global__ __launch_bounds__(256) void attn_k(const unsigned* __restrict__ bitmap,
                                              const unsigned short* __restrict__ gbf,
                                              const float* __restrict__ el_,
                                              const float* __restrict__ er_,
                                              float* __restrict__ out) {
  __shared__ unsigned short jl[4][MAXJ];     // 2KB
  const int t = threadIdx.x, wv = t >> 6, l = t & 63;
  const int i = blockIdx.x * 4 + wv;

  unsigned w0 = bitmap[i * 128 + l];
  unsigned w1 = bitmap[i * 128 + 64 + l];
  int cnt = __popc(w0) + __popc(w1);
  int incl = cnt;
#pragma unroll
  for (int d = 1; d < 64; d <<= 1) {
    int u = __shfl_up(incl, d);
    if (l >= d) incl += u;
  }
  int total = __shfl(incl, 63);
  if (total > MAXJ) total = MAXJ;
  int off = incl - cnt;
  unsigned short* J = jl[wv];
  while (w0) {
    int b = __ffs(w0) - 1;
    if (off < MAXJ) J[off] = (unsigned short)(l * 32 + b);
    ++off; w0 &= w0 - 1;
  }
  while (w1) {
    int b = __ffs(w1) - 1;
    if (off < MAXJ) J[off] = (unsigned short)((64 + l) * 32 + b);
    ++off; w1 &= w1 - 1;
  }
  __syncthreads();

  const int hh = l >> 3;
  const float elh = el_[i * NH + hh];
  const unsigned short* gp = gbf + (size_t)l * 4;
  f32x4 accA = {}, accB = {};
  float den0 = 0.f, den1 = 0.f;
  int k = 0;
  for (; k + 4 <= total; k += 4) {           // 4-way MLP: 4 rows + 4 er in flight
    int j0 = J[k], j1 = J[k + 1], j2 = J[k + 2], j3 = J[k + 3];
    float e0 = elh + er_[j0 * NH + hh];
    float e1 = elh + er_[j1 * NH + hh];
    float e2 = elh + er_[j2 * NH + hh];
    float e3 = elh + er_[j3 * NH + hh];
    ushort4 g0 = *(const ushort4*)(gp + (size_t)j0 * HF);
    ushort4 g1 = *(const ushort4*)(gp + (size_t)j1 * HF);
    ushort4 g2 = *(const ushort4*)(gp + (size_t)j2 * HF);
    ushort4 g3 = *(const ushort4*)(gp + (size_t)j3 * HF);
    float l0 = e0 > 0.f ? e0 : SLOPE * e0;
    float l1 = e1 > 0.f ? e1 : SLOPE * e1;
    float l2 = e2 > 0.f ? e2 : SLOPE * e2;
    float l3 = e3 > 0.f ? e3 : SLOPE * e3;
    float wg0 = __expf(l0), wg1 = __expf(l1), wg2 = __expf(l2), wg3 = __expf(l3);
    den0 += wg0 + wg2; den1 += wg1 + wg3;
    accA[0] += wg0 * bf2f(g0.x); accB[0] += wg1 * bf2f(g1.x);
    accA[1] += wg0 * bf2f(g0.y); accB[1] += wg1 * bf2f(g1.y);
    accA[2] += wg0 * bf2f(g0.z); accB[2] += wg1 * bf2f(g1.z);
    accA[3] += wg0 * bf2f(g0.w); accB[3] += wg1 * bf2f(g1.w);
    accA[0] += wg2 * bf2f(g2.x); accB[0] += wg3 * bf2f(g3.x);
    accA[1] += wg2 * bf2f(g2.y); accB[1] += wg3 * bf2f(g3.y);
    accA[2] += wg2 * bf2f(g2.z); accB[2] += wg3 * bf2f(g3.z);
    accA[3] += wg2 * bf2f(g2.w); accB[3] += wg3 * bf2f(g3.w);
  }
  for (; k < total; ++k) {
    int j0 = J[k];
    float e0 = elh + er_[j0 * NH + hh];
    float l0 = e0 > 0.f ? e0 : SLOPE * e0;
    float wg0 = __expf(l0);
    ushort4 g0 = *(const ushort4*)(gp + (size_t)j0 * HF);
    den0 += wg0;
    accA[0] += wg0 * bf2f(g0.x); accA[1] += wg0 * bf2f(g0.y);
    accA[2] += wg0 * bf2f(g0.z); accA[3] += wg0 * bf2f(g0.w);
  }
  float inv = 1.f / (den0 + den1);
  float4 o = make_float4((accA[0] + accB[0]) * inv, (accA[1] + accB[1]) * inv,
                         (accA[2] + accB[2]) * inv, (accA[3] + accB[3]) * inv);
  *(float4*)&out[(size_t)i * HF + l * 4] = o;
}

extern "C" void kernel_launch(void* const* d_in, const int* in_sizes, int n_in,
                              void* d_out, int out_size, void* d_ws, size_t ws_size,
                              hipStream_t stream) {
  const float* h      = (const float*)d_in[0];
  const int*   ei     = (const int*)d_in[1];
  const float* mask   = (const float*)d_in[2];
  const float* W_fc   = (const float*)d_in[3];
  const float* W_attn = (const float*)d_in[4];
  float* out = (float*)d_out;

  char* ws = (char*)d_ws;
  unsigned* bitmap      = (unsigned*)ws;                                          // 2 MB
  unsigned short* gbf   = (unsigned short*)(ws + (size_t)2 * 1024 * 1024);        // 2 MB
  float* el             = (float*)(ws + (size_t)4 * 1024 * 1024);                 // 128 KB
  float* er             = (float*)(ws + (size_t)4 * 1024 * 1024 + 128 * 1024);    // 128 KB
  unsigned short* Btbf  = (unsigned short*)(ws + (size_t)4 * 1024 * 1024 + 256 * 1024);  // 256 KB

  prep_k<<<640, 256, 0, stream>>>(W_fc, bitmap, Btbf);
  gemm_adj_k<<<1024 + 528, 256, 0, stream>>>(h, Btbf, W_attn, gbf, el, er, ei, mask, bitmap);
  attn_k<<<NN / 4, 256, 0, stream>>>(bitmap, gbf, el, er, out);
}

// Round 13
// 35.420 us; speedup vs baseline: 4.7974x; 1.3697x over previous
//
#include <hip/hip_runtime.h>
#include <stdint.h>

#define NN   4096
#define NE   131072
#define KIN  512
#define NH   8
#define HF   256
#define SLOPE 0.2f
#define MAXJ 256

typedef __attribute__((ext_vector_type(8))) short bf16x8;
typedef __attribute__((ext_vector_type(4))) float f32x4;

// ws layout: [0,2MB) bitmap | [2,4MB) gbf bf16 | [4MB,+128K) el | +128K er |
//            [4.25MB,+256K) Btbf (W_fc^T bf16)

__device__ __forceinline__ unsigned short f2bf(float x) {  // RTN-even f32->bf16
  unsigned u = __builtin_bit_cast(unsigned, x);
  u += 0x7FFFu + ((u >> 16) & 1u);
  return (unsigned short)(u >> 16);
}
__device__ __forceinline__ float bf2f(unsigned short x) {
  unsigned u = ((unsigned)x) << 16;
  return __builtin_bit_cast(float, u);
}
__device__ __forceinline__ unsigned pack2(float lo, float hi) {
  return (unsigned)f2bf(lo) | ((unsigned)f2bf(hi) << 16);
}

// K1: blocks 0..511 clear bitmap; 512..639 W_fc -> B^T bf16 (32x32 tile transpose)
__global__ __launch_bounds__(256) void prep_k(const float* __restrict__ B,
                                              unsigned* __restrict__ bitmap,
                                              unsigned short* __restrict__ Btbf) {
  __shared__ float tile[32][33];
  const int b = blockIdx.x, t = threadIdx.x;
  if (b < 512) {
    ((float4*)bitmap)[b * 256 + t] = make_float4(0.f, 0.f, 0.f, 0.f);
  } else {
    int bb = b - 512;
    int k0 = (bb >> 3) * 32, n0 = (bb & 7) * 32;
    int lr = t >> 3, lc = (t & 7) * 4;
    float4 v = *(const float4*)&B[(size_t)(k0 + lr) * HF + n0 + lc];
    tile[lr][lc] = v.x; tile[lr][lc + 1] = v.y; tile[lr][lc + 2] = v.z; tile[lr][lc + 3] = v.w;
    __syncthreads();
    ushort4 o;
    o.x = f2bf(tile[lc + 0][lr]); o.y = f2bf(tile[lc + 1][lr]);
    o.z = f2bf(tile[lc + 2][lr]); o.w = f2bf(tile[lc + 3][lr]);
    *(ushort4*)&Btbf[(size_t)(n0 + lr) * KIN + k0 + lc] = o;
  }
}

// K2: blocks 0..1023 = 32x32 MFMA GEMM tiles (128 M x 8 heads).
//     FULL-K LDS staging: A[32][512]+B[32][512] bf16 (64KB), ONE barrier, then
//     16 MFMA steps with zero syncs (R11 PMC: 8-barrier version was barrier-
//     latency-bound at 4.5% MfmaUtil; R12 reg-direct was coalescing-bound).
//     16B-slot XOR swizzle (c8 ^ (row&7)); B staged via global_load_lds with
//     pre-swizzled per-lane SOURCE (rule #21), A reg-staged (f32->bf16 pack).
//     Fused el/er epilogue. Blocks 1024..1551 = build_adj (bitmap atomicOr).
__global__ __launch_bounds__(256) void gemm_adj_k(const float* __restrict__ h,
                                                  const unsigned short* __restrict__ Bt,
                                                  const float* __restrict__ Wa,
                                                  unsigned short* __restrict__ gbf,
                                                  float* __restrict__ el,
                                                  float* __restrict__ er,
                                                  const int* __restrict__ ei,
                                                  const float* __restrict__ mask,
                                                  unsigned* __restrict__ bitmap) {
  __shared__ unsigned short As[32 * KIN];   // 32KB, swizzled 16B slots
  __shared__ unsigned short Bs[32 * KIN];   // 32KB
  __shared__ float red[128];
  const int bx = blockIdx.x, t = threadIdx.x;
  if (bx >= 1024) {  // ---- build_adj: NE+NN = 135168 = 528*256 exactly ----
    int k = (bx - 1024) * 256 + t;
    int s, d; float m;
    if (k < NE) { s = ei[k]; d = ei[NE + k]; m = mask[k]; }
    else        { s = k - NE; d = s; m = 1.0f; }   // diagonal forced to 1
    if (m != 0.0f) atomicOr(&bitmap[s * 128 + (d >> 5)], 1u << (d & 31));
    return;
  }
  // ---- gemm: 32x32 tile, gy selects the head ----
  const int gx = bx & 127, gy = bx >> 7;
  const int row0 = gx * 32, col0 = gy * 32;
  const int w = t >> 6, l = t & 63;
  const int wr = w >> 1, wc = w & 1;

  // ---- stage B: 8 wave-iterations of global_load_lds; dest linear chunk
  //      q = it*256 + t; LDS slot s holds logical chunk c8 = s ^ (row&7),
  //      so SOURCE is pre-swizzled (rule #21: both-sides-or-neither).
  {
    const float4* A4 = (const float4*)&h[(size_t)row0 * KIN];  // tile-linear quads
#pragma unroll
    for (int it = 0; it < 8; ++it) {
      int q   = it * 256 + t;            // dest chunk (16B units)
      int row = q >> 6;                  // 64 chunks per row
      int sc8 = (q & 63) ^ (row & 7);    // source logical chunk
      __builtin_amdgcn_global_load_lds(
          (const __attribute__((address_space(1))) unsigned int*)
              (&Bt[(size_t)(col0 + row) * KIN + sc8 * 8]),
          (__attribute__((address_space(3))) unsigned int*)
              (&Bs[(it * 256 + (t & ~63)) * 8]), 16, 0, 0);
      // ---- stage A (interleaved): pair p covers floats [p*8, p*8+8) of the tile
      int p   = it * 256 + t;
      float4 v0 = A4[2 * p], v1 = A4[2 * p + 1];
      int arw = p >> 6, ac8 = p & 63;
      uint4 w4 = {pack2(v0.x, v0.y), pack2(v0.z, v0.w),
                  pack2(v1.x, v1.y), pack2(v1.z, v1.w)};
      *(uint4*)&As[arw * KIN + ((ac8 ^ (arw & 7)) << 3)] = w4;
    }
  }
  __syncthreads();   // single staging barrier (drains vmcnt+lgkmcnt)

  const int lrow = l & 15, kg = l >> 4;
  const int ar = wr * 16 + lrow, br = wc * 16 + lrow;
  const int akey = ar & 7, bkey = br & 7;
  f32x4 acc = {};
#pragma unroll
  for (int ks = 0; ks < 16; ++ks) {      // same k-chunk order as R10 -> bitwise-identical
    int c8 = ks * 4 + kg;
    bf16x8 a = *(const bf16x8*)&As[ar * KIN + ((c8 ^ akey) << 3)];
    bf16x8 b = *(const bf16x8*)&Bs[br * KIN + ((c8 ^ bkey) << 3)];
    acc = __builtin_amdgcn_mfma_f32_16x16x32_bf16(a, b, acc, 0, 0, 0);
  }

  // C/D: col=lane&15, row=(lane>>4)*4+q  [m89-verified]
  const int crow = (l >> 4) * 4, ccol = l & 15;
  const int gr0 = row0 + wr * 16 + crow, gc = col0 + wc * 16 + ccol;
#pragma unroll
  for (int q = 0; q < 4; ++q) gbf[(size_t)(gr0 + q) * HF + gc] = f2bf(acc[q]);

  // fused el/er: this block's 32 cols == head gy's full f range
  const int f = wc * 16 + ccol;
  const float wal = Wa[f], war = Wa[32 + f];
#pragma unroll
  for (int q = 0; q < 4; ++q) {
    float pel = acc[q] * wal, per = acc[q] * war;
#pragma unroll
    for (int m = 8; m >= 1; m >>= 1) { pel += __shfl_xor(pel, m); per += __shfl_xor(per, m); }
    if (ccol == 0) {
      int rl = wr * 16 + crow + q;
      red[wc * 32 + rl] = pel;
      red[64 + wc * 32 + rl] = per;
    }
  }
  __syncthreads();
  if (t < 32) {
    el[(row0 + t) * NH + gy] = red[t] + red[32 + t];
    er[(row0 + t) * NH + gy] = red[64 + t] + red[96 + t];
  }
}

// K3: one WAVE per row (4 rows/block). Lane l owns output elems [l*4, l*4+4)
// (head l>>3). Wave-local bitmap expand; 4-way MLP gather loop with two
// independent accumulator pairs. No max-subtraction: |e| small -> exp f32-safe.
__global__ __launch_bounds__(256) void attn_k(const unsigned* __restrict__ bitmap,
                                              const unsigned short* __restrict__ gbf,
                                              const float* __restrict__ el_,
                                              const float* __restrict__ er_,
                                              float* __restrict__ out) {
  __shared__ unsigned short jl[4][MAXJ];     // 2KB
  const int t = threadIdx.x, wv = t >> 6, l = t & 63;
  const int i = blockIdx.x * 4 + wv;

  unsigned w0 = bitmap[i * 128 + l];
  unsigned w1 = bitmap[i * 128 + 64 + l];
  int cnt = __popc(w0) + __popc(w1);
  int incl = cnt;
#pragma unroll
  for (int d = 1; d < 64; d <<= 1) {
    int u = __shfl_up(incl, d);
    if (l >= d) incl += u;
  }
  int total = __shfl(incl, 63);
  if (total > MAXJ) total = MAXJ;
  int off = incl - cnt;
  unsigned short* J = jl[wv];
  while (w0) {
    int b = __ffs(w0) - 1;
    if (off < MAXJ) J[off] = (unsigned short)(l * 32 + b);
    ++off; w0 &= w0 - 1;
  }
  while (w1) {
    int b = __ffs(w1) - 1;
    if (off < MAXJ) J[off] = (unsigned short)((64 + l) * 32 + b);
    ++off; w1 &= w1 - 1;
  }
  __syncthreads();

  const int hh = l >> 3;
  const float elh = el_[i * NH + hh];
  const unsigned short* gp = gbf + (size_t)l * 4;
  f32x4 accA = {}, accB = {};
  float den0 = 0.f, den1 = 0.f;
  int k = 0;
  for (; k + 4 <= total; k += 4) {           // 4-way MLP: 4 rows + 4 er in flight
    int j0 = J[k], j1 = J[k + 1], j2 = J[k + 2], j3 = J[k + 3];
    float e0 = elh + er_[j0 * NH + hh];
    float e1 = elh + er_[j1 * NH + hh];
    float e2 = elh + er_[j2 * NH + hh];
    float e3 = elh + er_[j3 * NH + hh];
    ushort4 g0 = *(const ushort4*)(gp + (size_t)j0 * HF);
    ushort4 g1 = *(const ushort4*)(gp + (size_t)j1 * HF);
    ushort4 g2 = *(const ushort4*)(gp + (size_t)j2 * HF);
    ushort4 g3 = *(const ushort4*)(gp + (size_t)j3 * HF);
    float l0 = e0 > 0.f ? e0 : SLOPE * e0;
    float l1 = e1 > 0.f ? e1 : SLOPE * e1;
    float l2 = e2 > 0.f ? e2 : SLOPE * e2;
    float l3 = e3 > 0.f ? e3 : SLOPE * e3;
    float wg0 = __expf(l0), wg1 = __expf(l1), wg2 = __expf(l2), wg3 = __expf(l3);
    den0 += wg0 + wg2; den1 += wg1 + wg3;
    accA[0] += wg0 * bf2f(g0.x); accB[0] += wg1 * bf2f(g1.x);
    accA[1] += wg0 * bf2f(g0.y); accB[1] += wg1 * bf2f(g1.y);
    accA[2] += wg0 * bf2f(g0.z); accB[2] += wg1 * bf2f(g1.z);
    accA[3] += wg0 * bf2f(g0.w); accB[3] += wg1 * bf2f(g1.w);
    accA[0] += wg2 * bf2f(g2.x); accB[0] += wg3 * bf2f(g3.x);
    accA[1] += wg2 * bf2f(g2.y); accB[1] += wg3 * bf2f(g3.y);
    accA[2] += wg2 * bf2f(g2.z); accB[2] += wg3 * bf2f(g3.z);
    accA[3] += wg2 * bf2f(g2.w); accB[3] += wg3 * bf2f(g3.w);
  }
  for (; k < total; ++k) {
    int j0 = J[k];
    float e0 = elh + er_[j0 * NH + hh];
    float l0 = e0 > 0.f ? e0 : SLOPE * e0;
    float wg0 = __expf(l0);
    ushort4 g0 = *(const ushort4*)(gp + (size_t)j0 * HF);
    den0 += wg0;
    accA[0] += wg0 * bf2f(g0.x); accA[1] += wg0 * bf2f(g0.y);
    accA[2] += wg0 * bf2f(g0.z); accA[3] += wg0 * bf2f(g0.w);
  }
  float inv = 1.f / (den0 + den1);
  float4 o = make_float4((accA[0] + accB[0]) * inv, (accA[1] + accB[1]) * inv,
                         (accA[2] + accB[2]) * inv, (accA[3] + accB[3]) * inv);
  *(float4*)&out[(size_t)i * HF + l * 4] = o;
}

extern "C" void kernel_launch(void* const* d_in, const int* in_sizes, int n_in,
                              void* d_out, int out_size, void* d_ws, size_t ws_size,
                              hipStream_t stream) {
  const float* h      = (const float*)d_in[0];
  const int*   ei     = (const int*)d_in[1];
  const float* mask   = (const float*)d_in[2];
  const float* W_fc   = (const float*)d_in[3];
  const float* W_attn = (const float*)d_in[4];
  float* out = (float*)d_out;

  char* ws = (char*)d_ws;
  unsigned* bitmap      = (unsigned*)ws;                                          // 2 MB
  unsigned short* gbf   = (unsigned short*)(ws + (size_t)2 * 1024 * 1024);        // 2 MB
  float* el             = (float*)(ws + (size_t)4 * 1024 * 1024);                 // 128 KB
  float* er             = (float*)(ws + (size_t)4 * 1024 * 1024 + 128 * 1024);    // 128 KB
  unsigned short* Btbf  = (unsigned short*)(ws + (size_t)4 * 1024 * 1024 + 256 * 1024);  // 256 KB

  prep_k<<<640, 256, 0, stream>>>(W_fc, bitmap, Btbf);
  gemm_adj_k<<<1024 + 528, 256, 0, stream>>>(h, Btbf, W_attn, gbf, el, er, ei, mask, bitmap);
  attn_k<<<NN / 4, 256, 0, stream>>>(bitmap, gbf, el, er, out);
}

// Round 14
// 33.450 us; speedup vs baseline: 5.0799x; 1.0589x over previous
//
#include <hip/hip_runtime.h>
#include <stdint.h>

#define NN   4096
#define NE   131072
#define KIN  512
#define NH   8
#define HF   256
#define SLOPE 0.2f
#define MAXJ 256

typedef __attribute__((ext_vector_type(8))) short bf16x8;
typedef __attribute__((ext_vector_type(4))) float f32x4;

// ws layout: [0,2MB) bitmap | [2,4MB) gbf bf16 | [4MB,+128K) el | +128K er |
//            [4.25MB,+256K) Btbf (W_fc^T bf16)

__device__ __forceinline__ unsigned short f2bf(float x) {  // RTN-even f32->bf16
  unsigned u = __builtin_bit_cast(unsigned, x);
  u += 0x7FFFu + ((u >> 16) & 1u);
  return (unsigned short)(u >> 16);
}
__device__ __forceinline__ float bf2f(unsigned short x) {
  unsigned u = ((unsigned)x) << 16;
  return __builtin_bit_cast(float, u);
}
__device__ __forceinline__ unsigned pack2(float lo, float hi) {
  return (unsigned)f2bf(lo) | ((unsigned)f2bf(hi) << 16);
}

// K1: blocks 0..127 clear bitmap (4 float4/thread, stride-256 coalesced);
//     blocks 128..255 W_fc -> B^T bf16 (32x32 tile transpose)
__global__ __launch_bounds__(256) void prep_k(const float* __restrict__ B,
                                              unsigned* __restrict__ bitmap,
                                              unsigned short* __restrict__ Btbf) {
  __shared__ float tile[32][33];
  const int b = blockIdx.x, t = threadIdx.x;
  if (b < 128) {
    float4* p = (float4*)bitmap + (size_t)b * 1024;
#pragma unroll
    for (int it = 0; it < 4; ++it)
      p[it * 256 + t] = make_float4(0.f, 0.f, 0.f, 0.f);
  } else {
    int bb = b - 128;
    int k0 = (bb >> 3) * 32, n0 = (bb & 7) * 32;
    int lr = t >> 3, lc = (t & 7) * 4;
    float4 v = *(const float4*)&B[(size_t)(k0 + lr) * HF + n0 + lc];
    tile[lr][lc] = v.x; tile[lr][lc + 1] = v.y; tile[lr][lc + 2] = v.z; tile[lr][lc + 3] = v.w;
    __syncthreads();
    ushort4 o;
    o.x = f2bf(tile[lc + 0][lr]); o.y = f2bf(tile[lc + 1][lr]);
    o.z = f2bf(tile[lc + 2][lr]); o.w = f2bf(tile[lc + 3][lr]);
    *(ushort4*)&Btbf[(size_t)(n0 + lr) * KIN + k0 + lc] = o;
  }
}

// K2: blocks 0..1023 = 32x32 MFMA GEMM tiles (128 M x 8 heads), BK=64, dbuf,
//     A reg-staged straight from h (f32->bf16 in-kernel), B via global_load_lds;
//     fused el/er epilogue. Blocks 1024..1551 = build_adj (bitmap atomicOr).
//     [R10-proven structure, verbatim]
__global__ __launch_bounds__(256) void gemm_adj_k(const float* __restrict__ h,
                                                  const unsigned short* __restrict__ Bt,
                                                  const float* __restrict__ Wa,
                                                  unsigned short* __restrict__ gbf,
                                                  float* __restrict__ el,
                                                  float* __restrict__ er,
                                                  const int* __restrict__ ei,
                                                  const float* __restrict__ mask,
                                                  unsigned* __restrict__ bitmap) {
  __shared__ unsigned short smem[2][4096];  // per buf: A[32][64]@0, B[32][64]@2048
  const int bx = blockIdx.x, t = threadIdx.x;
  if (bx >= 1024) {  // ---- build_adj: NE+NN = 135168 = 528*256 exactly ----
    int k = (bx - 1024) * 256 + t;
    int s, d; float m;
    if (k < NE) { s = ei[k]; d = ei[NE + k]; m = mask[k]; }
    else        { s = k - NE; d = s; m = 1.0f; }   // diagonal forced to 1
    if (m != 0.0f) atomicOr(&bitmap[s * 128 + (d >> 5)], 1u << (d & 31));
    return;
  }
  // ---- gemm: 32x32 tile, gy selects the head ----
  const int gx = bx & 127, gy = bx >> 7;
  const int row0 = gx * 32, col0 = gy * 32;
  const int w = t >> 6, l = t & 63;
  const int wr = w >> 1, wc = w & 1;

  const int srow = (w << 3) + (l >> 3);      // wave w stages rows 8w..8w+7
  const int sc   = l & 7;                    // linear k-chunk for A (swizzle on ds_write)
  const int aoff = srow * 64 + ((sc ^ (srow & 7)) << 3);   // swizzled LDS slot (ushorts)
  const float* gA = &h[(size_t)(row0 + srow) * KIN + sc * 8];
  const int schB = sc ^ (srow & 7);          // B source pre-swizzled (rule #21)
  const unsigned short* gB = &Bt[(size_t)(col0 + srow) * KIN + schB * 8];

#define BSTAGE(bf, ks)                                                                            \
  __builtin_amdgcn_global_load_lds(                                                               \
      (const __attribute__((address_space(1))) unsigned int*)(gB + (size_t)(ks) * 64),            \
      (__attribute__((address_space(3))) unsigned int*)(&smem[bf][2048 + w * 512]), 16, 0, 0)

  f32x4 acc = {};
  {
    float4 va0 = *(const float4*)(gA);
    float4 va1 = *(const float4*)(gA + 4);
    BSTAGE(0, 0);
    uint4 w4 = {pack2(va0.x, va0.y), pack2(va0.z, va0.w),
                pack2(va1.x, va1.y), pack2(va1.z, va1.w)};
    *(uint4*)&smem[0][aoff] = w4;
  }
  __syncthreads();

  const int lrow = l & 15, kg = l >> 4;
  const int ar = wr * 16 + lrow, br = wc * 16 + lrow;
  for (int ks = 0; ks < 8; ++ks) {
    const int bf = ks & 1;
    float4 na0, na1;
    if (ks < 7) {                            // issue next-step A loads early (T14)
      na0 = *(const float4*)(gA + (ks + 1) * 64);
      na1 = *(const float4*)(gA + (ks + 1) * 64 + 4);
      BSTAGE(bf ^ 1, ks + 1);
    }
    bf16x8 a0 = *(const bf16x8*)&smem[bf][ar * 64 + ((kg ^ (ar & 7)) << 3)];
    bf16x8 a1 = *(const bf16x8*)&smem[bf][ar * 64 + (((4 + kg) ^ (ar & 7)) << 3)];
    bf16x8 b0 = *(const bf16x8*)&smem[bf][2048 + br * 64 + ((kg ^ (br & 7)) << 3)];
    bf16x8 b1 = *(const bf16x8*)&smem[bf][2048 + br * 64 + (((4 + kg) ^ (br & 7)) << 3)];
    acc = __builtin_amdgcn_mfma_f32_16x16x32_bf16(a0, b0, acc, 0, 0, 0);
    acc = __builtin_amdgcn_mfma_f32_16x16x32_bf16(a1, b1, acc, 0, 0, 0);
    if (ks < 7) {                            // write-late into the other buffer
      uint4 w4 = {pack2(na0.x, na0.y), pack2(na0.z, na0.w),
                  pack2(na1.x, na1.y), pack2(na1.z, na1.w)};
      *(uint4*)&smem[bf ^ 1][aoff] = w4;
    }
    __syncthreads();
  }
#undef BSTAGE

  // C/D: col=lane&15, row=(lane>>4)*4+q  [m89-verified]
  const int crow = (l >> 4) * 4, ccol = l & 15;
  const int gr0 = row0 + wr * 16 + crow, gc = col0 + wc * 16 + ccol;
#pragma unroll
  for (int q = 0; q < 4; ++q) gbf[(size_t)(gr0 + q) * HF + gc] = f2bf(acc[q]);

  // fused el/er: this block's 32 cols == head gy's full f range
  float* red = (float*)smem;                 // reuse after final K-loop sync
  const int f = wc * 16 + ccol;
  const float wal = Wa[f], war = Wa[32 + f];
#pragma unroll
  for (int q = 0; q < 4; ++q) {
    float pel = acc[q] * wal, per = acc[q] * war;
#pragma unroll
    for (int m = 8; m >= 1; m >>= 1) { pel += __shfl_xor(pel, m); per += __shfl_xor(per, m); }
    if (ccol == 0) {
      int rl = wr * 16 + crow + q;
      red[wc * 32 + rl] = pel;
      red[64 + wc * 32 + rl] = per;
    }
  }
  __syncthreads();
  if (t < 32) {
    el[(row0 + t) * NH + gy] = red[t] + red[32 + t];
    er[(row0 + t) * NH + gy] = red[64 + t] + red[96 + t];
  }
}

// K3: one WAVE per row, now 8 rows/block (512 threads, 8 waves) -> grid 512,
// half the workgroup ramp. Wave-local logic identical to R10. Lane l owns
// output elems [l*4, l*4+4) (head l>>3). 4-way MLP gather loop.
__global__ __launch_bounds__(512) void attn_k(const unsigned* __restrict__ bitmap,
                                              const unsigned short* __restrict__ gbf,
                                              const float* __restrict__ el_,
                                              const float* __restrict__ er_,
                                              float* __restrict__ out) {
  __shared__ unsigned short jl[8][MAXJ];     // 4KB
  const int t = threadIdx.x, wv = t >> 6, l = t & 63;
  const int i = blockIdx.x * 8 + wv;

  unsigned w0 = bitmap[i * 128 + l];
  unsigned w1 = bitmap[i * 128 + 64 + l];
  int cnt = __popc(w0) + __popc(w1);
  int incl = cnt;
#pragma unroll
  for (int d = 1; d < 64; d <<= 1) {
    int u = __shfl_up(incl, d);
    if (l >= d) incl += u;
  }
  int total = __shfl(incl, 63);
  if (total > MAXJ) total = MAXJ;
  int off = incl - cnt;
  unsigned short* J = jl[wv];
  while (w0) {
    int b = __ffs(w0) - 1;
    if (off < MAXJ) J[off] = (unsigned short)(l * 32 + b);
    ++off; w0 &= w0 - 1;
  }
  while (w1) {
    int b = __ffs(w1) - 1;
    if (off < MAXJ) J[off] = (unsigned short)((64 + l) * 32 + b);
    ++off; w1 &= w1 - 1;
  }
  __syncthreads();

  const int hh = l >> 3;
  const float elh = el_[i * NH + hh];
  const unsigned short* gp = gbf + (size_t)l * 4;
  f32x4 accA = {}, accB = {};
  float den0 = 0.f, den1 = 0.f;
  int k = 0;
  for (; k + 4 <= total; k += 4) {           // 4-way MLP: 4 rows + 4 er in flight
    int j0 = J[k], j1 = J[k + 1], j2 = J[k + 2], j3 = J[k + 3];
    float e0 = elh + er_[j0 * NH + hh];
    float e1 = elh + er_[j1 * NH + hh];
    float e2 = elh + er_[j2 * NH + hh];
    float e3 = elh + er_[j3 * NH + hh];
    ushort4 g0 = *(const ushort4*)(gp + (size_t)j0 * HF);
    ushort4 g1 = *(const ushort4*)(gp + (size_t)j1 * HF);
    ushort4 g2 = *(const ushort4*)(gp + (size_t)j2 * HF);
    ushort4 g3 = *(const ushort4*)(gp + (size_t)j3 * HF);
    float l0 = e0 > 0.f ? e0 : SLOPE * e0;
    float l1 = e1 > 0.f ? e1 : SLOPE * e1;
    float l2 = e2 > 0.f ? e2 : SLOPE * e2;
    float l3 = e3 > 0.f ? e3 : SLOPE * e3;
    float wg0 = __expf(l0), wg1 = __expf(l1), wg2 = __expf(l2), wg3 = __expf(l3);
    den0 += wg0 + wg2; den1 += wg1 + wg3;
    accA[0] += wg0 * bf2f(g0.x); accB[0] += wg1 * bf2f(g1.x);
    accA[1] += wg0 * bf2f(g0.y); accB[1] += wg1 * bf2f(g1.y);
    accA[2] += wg0 * bf2f(g0.z); accB[2] += wg1 * bf2f(g1.z);
    accA[3] += wg0 * bf2f(g0.w); accB[3] += wg1 * bf2f(g1.w);
    accA[0] += wg2 * bf2f(g2.x); accB[0] += wg3 * bf2f(g3.x);
    accA[1] += wg2 * bf2f(g2.y); accB[1] += wg3 * bf2f(g3.y);
    accA[2] += wg2 * bf2f(g2.z); accB[2] += wg3 * bf2f(g3.z);
    accA[3] += wg2 * bf2f(g2.w); accB[3] += wg3 * bf2f(g3.w);
  }
  for (; k < total; ++k) {
    int j0 = J[k];
    float e0 = elh + er_[j0 * NH + hh];
    float l0 = e0 > 0.f ? e0 : SLOPE * e0;
    float wg0 = __expf(l0);
    ushort4 g0 = *(const ushort4*)(gp + (size_t)j0 * HF);
    den0 += wg0;
    accA[0] += wg0 * bf2f(g0.x); accA[1] += wg0 * bf2f(g0.y);
    accA[2] += wg0 * bf2f(g0.z); accA[3] += wg0 * bf2f(g0.w);
  }
  float inv = 1.f / (den0 + den1);
  float4 o = make_float4((accA[0] + accB[0]) * inv, (accA[1] + accB[1]) * inv,
                         (accA[2] + accB[2]) * inv, (accA[3] + accB[3]) * inv);
  *(float4*)&out[(size_t)i * HF + l * 4] = o;
}

extern "C" void kernel_launch(void* const* d_in, const int* in_sizes, int n_in,
                              void* d_out, int out_size, void* d_ws, size_t ws_size,
                              hipStream_t stream) {
  const float* h      = (const float*)d_in[0];
  const int*   ei     = (const int*)d_in[1];
  const float* mask   = (const float*)d_in[2];
  const float* W_fc   = (const float*)d_in[3];
  const float* W_attn = (const float*)d_in[4];
  float* out = (float*)d_out;

  char* ws = (char*)d_ws;
  unsigned* bitmap      = (unsigned*)ws;                                          // 2 MB
  unsigned short* gbf   = (unsigned short*)(ws + (size_t)2 * 1024 * 1024);        // 2 MB
  float* el             = (float*)(ws + (size_t)4 * 1024 * 1024);                 // 128 KB
  float* er             = (float*)(ws + (size_t)4 * 1024 * 1024 + 128 * 1024);    // 128 KB
  unsigned short* Btbf  = (unsigned short*)(ws + (size_t)4 * 1024 * 1024 + 256 * 1024);  // 256 KB

  prep_k<<<256, 256, 0, stream>>>(W_fc, bitmap, Btbf);
  gemm_adj_k<<<1024 + 528, 256, 0, stream>>>(h, Btbf, W_attn, gbf, el, er, ei, mask, bitmap);
  attn_k<<<NN / 8, 512, 0, stream>>>(bitmap, gbf, el, er, out);
}

// Round 15
// 33.256 us; speedup vs baseline: 5.1095x; 1.0058x over previous
//
#include <hip/hip_runtime.h>
#include <stdint.h>

#define NN   4096
#define NE   131072
#define KIN  512
#define NH   8
#define HF   256
#define SLOPE 0.2f
#define MAXJ 256

typedef __attribute__((ext_vector_type(8))) short bf16x8;
typedef __attribute__((ext_vector_type(4))) float f32x4;

// ws layout: [0,2MB) bitmap | [2,4MB) gbf bf16 | [4MB,+128K) el | +128K er |
//            [4.25MB,+256K) Btbf (W_fc^T bf16)

__device__ __forceinline__ unsigned short f2bf(float x) {  // RTN-even f32->bf16
  unsigned u = __builtin_bit_cast(unsigned, x);
  u += 0x7FFFu + ((u >> 16) & 1u);
  return (unsigned short)(u >> 16);
}
__device__ __forceinline__ float bf2f(unsigned short x) {
  unsigned u = ((unsigned)x) << 16;
  return __builtin_bit_cast(float, u);
}
__device__ __forceinline__ unsigned pack2(float lo, float hi) {
  return (unsigned)f2bf(lo) | ((unsigned)f2bf(hi) << 16);
}

// K1: blocks 0..127 clear bitmap (4 float4/thread); 128..255 W_fc -> B^T bf16
__global__ __launch_bounds__(256) void prep_k(const float* __restrict__ B,
                                              unsigned* __restrict__ bitmap,
                                              unsigned short* __restrict__ Btbf) {
  __shared__ float tile[32][33];
  const int b = blockIdx.x, t = threadIdx.x;
  if (b < 128) {
    float4* p = (float4*)bitmap + (size_t)b * 1024;
#pragma unroll
    for (int it = 0; it < 4; ++it)
      p[it * 256 + t] = make_float4(0.f, 0.f, 0.f, 0.f);
  } else {
    int bb = b - 128;
    int k0 = (bb >> 3) * 32, n0 = (bb & 7) * 32;
    int lr = t >> 3, lc = (t & 7) * 4;
    float4 v = *(const float4*)&B[(size_t)(k0 + lr) * HF + n0 + lc];
    tile[lr][lc] = v.x; tile[lr][lc + 1] = v.y; tile[lr][lc + 2] = v.z; tile[lr][lc + 3] = v.w;
    __syncthreads();
    ushort4 o;
    o.x = f2bf(tile[lc + 0][lr]); o.y = f2bf(tile[lc + 1][lr]);
    o.z = f2bf(tile[lc + 2][lr]); o.w = f2bf(tile[lc + 3][lr]);
    *(ushort4*)&Btbf[(size_t)(n0 + lr) * KIN + k0 + lc] = o;
  }
}

// K2: blocks 0..511 = 32x64 MFMA GEMM tiles (128 M x 4 col-tiles = 2 heads each),
//     BK=64 dbuf; A reg-staged (R10 formulas verbatim, now 4x instead of 8x
//     redundant), B 64 rows via 2x global_load_lds/wave (pre-swizzled source,
//     rule #21). Each wave covers one head's full 32-col f-range -> el/er
//     epilogue fully in-wave (no LDS pass). K-chunk MFMA order per output
//     element identical to R10 -> bitwise-identical acc.
//     Blocks 512..1039 = build_adj (bitmap atomicOr).
__global__ __launch_bounds__(256) void gemm_adj_k(const float* __restrict__ h,
                                                  const unsigned short* __restrict__ Bt,
                                                  const float* __restrict__ Wa,
                                                  unsigned short* __restrict__ gbf,
                                                  float* __restrict__ el,
                                                  float* __restrict__ er,
                                                  const int* __restrict__ ei,
                                                  const float* __restrict__ mask,
                                                  unsigned* __restrict__ bitmap) {
  __shared__ unsigned short smem[2][6144];  // per buf: A[32][64]@0, B[64][64]@2048
  const int bx = blockIdx.x, t = threadIdx.x;
  if (bx >= 512) {  // ---- build_adj: NE+NN = 135168 = 528*256 exactly ----
    int k = (bx - 512) * 256 + t;
    int s, d; float m;
    if (k < NE) { s = ei[k]; d = ei[NE + k]; m = mask[k]; }
    else        { s = k - NE; d = s; m = 1.0f; }   // diagonal forced to 1
    if (m != 0.0f) atomicOr(&bitmap[s * 128 + (d >> 5)], 1u << (d & 31));
    return;
  }
  // ---- gemm: 32x64 tile; gy*2+wc selects the head ----
  const int gx = bx & 127, gy = bx >> 7;          // 128 M-tiles x 4 col-tiles
  const int row0 = gx * 32, col0 = gy * 64;
  const int w = t >> 6, l = t & 63;
  const int wr = w >> 1, wc = w & 1;              // wave: rows wr*16..+16, cols wc*32..+32

  const int srow = t >> 3;                        // A stage: row 0..31, chunk t&7 (R10 verbatim)
  const int sc   = l & 7;
  const int aoff = srow * 64 + (((t & 7) ^ (srow & 7)) << 3);
  const float* gA = &h[(size_t)(row0 + srow) * KIN + (t & 7) * 8];
  // B stage: wave w, lane l -> rows (8w + l>>3) and (32 + 8w + l>>3); key (row&7) invariant +32
  const int bsrow = (w << 3) + (l >> 3);
  const int schB  = sc ^ (bsrow & 7);
  const unsigned short* gB0 = &Bt[(size_t)(col0 + bsrow) * KIN + schB * 8];
  const unsigned short* gB1 = &Bt[(size_t)(col0 + 32 + bsrow) * KIN + schB * 8];

#define BSTAGE(bf, ks)                                                                            \
  do {                                                                                            \
    __builtin_amdgcn_global_load_lds(                                                             \
        (const __attribute__((address_space(1))) unsigned int*)(gB0 + (size_t)(ks) * 64),         \
        (__attribute__((address_space(3))) unsigned int*)(&smem[bf][2048 + w * 512]), 16, 0, 0);  \
    __builtin_amdgcn_global_load_lds(                                                             \
        (const __attribute__((address_space(1))) unsigned int*)(gB1 + (size_t)(ks) * 64),         \
        (__attribute__((address_space(3))) unsigned int*)(&smem[bf][4096 + w * 512]), 16, 0, 0);  \
  } while (0)

  f32x4 acc0 = {}, acc1 = {};                     // col-frags wc*32+0..16, +16..32
  {
    float4 va0 = *(const float4*)(gA);
    float4 va1 = *(const float4*)(gA + 4);
    BSTAGE(0, 0);
    uint4 w4 = {pack2(va0.x, va0.y), pack2(va0.z, va0.w),
                pack2(va1.x, va1.y), pack2(va1.z, va1.w)};
    *(uint4*)&smem[0][aoff] = w4;
  }
  __syncthreads();

  const int lrow = l & 15, kg = l >> 4;
  const int ar  = wr * 16 + lrow;
  const int br0 = wc * 32 + lrow, br1 = wc * 32 + 16 + lrow;
  for (int ks = 0; ks < 8; ++ks) {
    const int bf = ks & 1;
    float4 na0, na1;
    if (ks < 7) {                                 // issue next-step A loads early (T14)
      na0 = *(const float4*)(gA + (ks + 1) * 64);
      na1 = *(const float4*)(gA + (ks + 1) * 64 + 4);
      BSTAGE(bf ^ 1, ks + 1);
    }
    bf16x8 a0 = *(const bf16x8*)&smem[bf][ar * 64 + ((kg ^ (ar & 7)) << 3)];
    bf16x8 a1 = *(const bf16x8*)&smem[bf][ar * 64 + (((4 + kg) ^ (ar & 7)) << 3)];
    bf16x8 b00 = *(const bf16x8*)&smem[bf][2048 + br0 * 64 + ((kg ^ (br0 & 7)) << 3)];
    bf16x8 b01 = *(const bf16x8*)&smem[bf][2048 + br0 * 64 + (((4 + kg) ^ (br0 & 7)) << 3)];
    bf16x8 b10 = *(const bf16x8*)&smem[bf][2048 + br1 * 64 + ((kg ^ (br1 & 7)) << 3)];
    bf16x8 b11 = *(const bf16x8*)&smem[bf][2048 + br1 * 64 + (((4 + kg) ^ (br1 & 7)) << 3)];
    acc0 = __builtin_amdgcn_mfma_f32_16x16x32_bf16(a0, b00, acc0, 0, 0, 0);
    acc0 = __builtin_amdgcn_mfma_f32_16x16x32_bf16(a1, b01, acc0, 0, 0, 0);
    acc1 = __builtin_amdgcn_mfma_f32_16x16x32_bf16(a0, b10, acc1, 0, 0, 0);
    acc1 = __builtin_amdgcn_mfma_f32_16x16x32_bf16(a1, b11, acc1, 0, 0, 0);
    if (ks < 7) {                                 // write-late into the other buffer
      uint4 w4 = {pack2(na0.x, na0.y), pack2(na0.z, na0.w),
                  pack2(na1.x, na1.y), pack2(na1.z, na1.w)};
      *(uint4*)&smem[bf ^ 1][aoff] = w4;
    }
    __syncthreads();
  }
#undef BSTAGE

  // C/D: col=lane&15, row=(lane>>4)*4+q  [m89-verified]
  const int crow = (l >> 4) * 4, ccol = l & 15;
  const int gr0 = row0 + wr * 16 + crow;
  const int gc0 = col0 + wc * 32 + ccol, gc1 = gc0 + 16;
#pragma unroll
  for (int q = 0; q < 4; ++q) {
    gbf[(size_t)(gr0 + q) * HF + gc0] = f2bf(acc0[q]);
    gbf[(size_t)(gr0 + q) * HF + gc1] = f2bf(acc1[q]);
  }

  // fused el/er: wave covers head (gy*2+wc)'s FULL f range: f = cfrag*16 + ccol
  const int head = (gy << 1) + wc;
  const float wal0 = Wa[ccol],      wal1 = Wa[16 + ccol];
  const float war0 = Wa[32 + ccol], war1 = Wa[48 + ccol];
#pragma unroll
  for (int q = 0; q < 4; ++q) {
    float pel = acc0[q] * wal0 + acc1[q] * wal1;
    float per = acc0[q] * war0 + acc1[q] * war1;
#pragma unroll
    for (int m = 8; m >= 1; m >>= 1) { pel += __shfl_xor(pel, m); per += __shfl_xor(per, m); }
    if (ccol == 0) {
      el[(gr0 + q) * NH + head] = pel;
      er[(gr0 + q) * NH + head] = per;
    }
  }
}

// K3: one WAVE per row, 8 rows/block (512 threads). Lane l owns output elems
// [l*4, l*4+4) (head l>>3). Wave-local bitmap expand; 4-way MLP gather loop.
__global__ __launch_bounds__(512) void attn_k(const unsigned* __restrict__ bitmap,
                                              const unsigned short* __restrict__ gbf,
                                              const float* __restrict__ el_,
                                              const float* __restrict__ er_,
                                              float* __restrict__ out) {
  __shared__ unsigned short jl[8][MAXJ];     // 4KB
  const int t = threadIdx.x, wv = t >> 6, l = t & 63;
  const int i = blockIdx.x * 8 + wv;

  unsigned w0 = bitmap[i * 128 + l];
  unsigned w1 = bitmap[i * 128 + 64 + l];
  int cnt = __popc(w0) + __popc(w1);
  int incl = cnt;
#pragma unroll
  for (int d = 1; d < 64; d <<= 1) {
    int u = __shfl_up(incl, d);
    if (l >= d) incl += u;
  }
  int total = __shfl(incl, 63);
  if (total > MAXJ) total = MAXJ;
  int off = incl - cnt;
  unsigned short* J = jl[wv];
  while (w0) {
    int b = __ffs(w0) - 1;
    if (off < MAXJ) J[off] = (unsigned short)(l * 32 + b);
    ++off; w0 &= w0 - 1;
  }
  while (w1) {
    int b = __ffs(w1) - 1;
    if (off < MAXJ) J[off] = (unsigned short)((64 + l) * 32 + b);
    ++off; w1 &= w1 - 1;
  }
  __syncthreads();

  const int hh = l >> 3;
  const float elh = el_[i * NH + hh];
  const unsigned short* gp = gbf + (size_t)l * 4;
  f32x4 accA = {}, accB = {};
  float den0 = 0.f, den1 = 0.f;
  int k = 0;
  for (; k + 4 <= total; k += 4) {           // 4-way MLP: 4 rows + 4 er in flight
    int j0 = J[k], j1 = J[k + 1], j2 = J[k + 2], j3 = J[k + 3];
    float e0 = elh + er_[j0 * NH + hh];
    float e1 = elh + er_[j1 * NH + hh];
    float e2 = elh + er_[j2 * NH + hh];
    float e3 = elh + er_[j3 * NH + hh];
    ushort4 g0 = *(const ushort4*)(gp + (size_t)j0 * HF);
    ushort4 g1 = *(const ushort4*)(gp + (size_t)j1 * HF);
    ushort4 g2 = *(const ushort4*)(gp + (size_t)j2 * HF);
    ushort4 g3 = *(const ushort4*)(gp + (size_t)j3 * HF);
    float l0 = e0 > 0.f ? e0 : SLOPE * e0;
    float l1 = e1 > 0.f ? e1 : SLOPE * e1;
    float l2 = e2 > 0.f ? e2 : SLOPE * e2;
    float l3 = e3 > 0.f ? e3 : SLOPE * e3;
    float wg0 = __expf(l0), wg1 = __expf(l1), wg2 = __expf(l2), wg3 = __expf(l3);
    den0 += wg0 + wg2; den1 += wg1 + wg3;
    accA[0] += wg0 * bf2f(g0.x); accB[0] += wg1 * bf2f(g1.x);
    accA[1] += wg0 * bf2f(g0.y); accB[1] += wg1 * bf2f(g1.y);
    accA[2] += wg0 * bf2f(g0.z); accB[2] += wg1 * bf2f(g1.z);
    accA[3] += wg0 * bf2f(g0.w); accB[3] += wg1 * bf2f(g1.w);
    accA[0] += wg2 * bf2f(g2.x); accB[0] += wg3 * bf2f(g3.x);
    accA[1] += wg2 * bf2f(g2.y); accB[1] += wg3 * bf2f(g3.y);
    accA[2] += wg2 * bf2f(g2.z); accB[2] += wg3 * bf2f(g3.z);
    accA[3] += wg2 * bf2f(g2.w); accB[3] += wg3 * bf2f(g3.w);
  }
  for (; k < total; ++k) {
    int j0 = J[k];
    float e0 = elh + er_[j0 * NH + hh];
    float l0 = e0 > 0.f ? e0 : SLOPE * e0;
    float wg0 = __expf(l0);
    ushort4 g0 = *(const ushort4*)(gp + (size_t)j0 * HF);
    den0 += wg0;
    accA[0] += wg0 * bf2f(g0.x); accA[1] += wg0 * bf2f(g0.y);
    accA[2] += wg0 * bf2f(g0.z); accA[3] += wg0 * bf2f(g0.w);
  }
  float inv = 1.f / (den0 + den1);
  float4 o = make_float4((accA[0] + accB[0]) * inv, (accA[1] + accB[1]) * inv,
                         (accA[2] + accB[2]) * inv, (accA[3] + accB[3]) * inv);
  *(float4*)&out[(size_t)i * HF + l * 4] = o;
}

extern "C" void kernel_launch(void* const* d_in, const int* in_sizes, int n_in,
                              void* d_out, int out_size, void* d_ws, size_t ws_size,
                              hipStream_t stream) {
  const float* h      = (const float*)d_in[0];
  const int*   ei     = (const int*)d_in[1];
  const float* mask   = (const float*)d_in[2];
  const float* W_fc   = (const float*)d_in[3];
  const float* W_attn = (const float*)d_in[4];
  float* out = (float*)d_out;

  char* ws = (char*)d_ws;
  unsigned* bitmap      = (unsigned*)ws;                                          // 2 MB
  unsigned short* gbf   = (unsigned short*)(ws + (size_t)2 * 1024 * 1024);        // 2 MB
  float* el             = (float*)(ws + (size_t)4 * 1024 * 1024);                 // 128 KB
  float* er             = (float*)(ws + (size_t)4 * 1024 * 1024 + 128 * 1024);    // 128 KB
  unsigned short* Btbf  = (unsigned short*)(ws + (size_t)4 * 1024 * 1024 + 256 * 1024);  // 256 KB

  prep_k<<<256, 256, 0, stream>>>(W_fc, bitmap, Btbf);
  gemm_adj_k<<<512 + 528, 256, 0, stream>>>(h, Btbf, W_attn, gbf, el, er, ei, mask, bitmap);
  attn_k<<<NN / 8, 512, 0, stream>>>(bitmap, gbf, el, er, out);
}